// Round 13
// baseline (37.579 us; speedup 1.0000x reference)
//
#include <hip/hip_runtime.h>
#include <stdint.h>

#define CN 144
#define VN 576
#define BN 1024
#define NITER 3
#define RCAP 32      // row-weight capacity, multiple of 4 (actual max ~28; R9-R12-proven)
#define NQ   (RCAP/4)
#define CCAP 8       // column-weight capacity (actual 4, rare 5)
#define TPB 192      // 3 waves; 576/192 = exactly 3 columns per thread

// ws layout (ints):
#define WS_RLEN 0                 // [0,144)   row lengths (raw)
#define WS_CCNT 144               // [144,720) per-column edge count (clamped to CCAP)
#define WS_CSC  720               // [720, 720+CCAP*VN) slot-major [j][v] = edge id

// edge id for (row-slot l, check c), quad layout: float index
// ((l>>2)*CN + c)*4 + (l&3) -> lane-consecutive float4 per (l>>2, c)
__device__ __forceinline__ int edge_id(int l, int c) {
    return (((l >> 2) * CN + c) << 2) | (l & 3);
}

// ---- single-node build: ONE block, all counters in LDS (no memset node, no
// cross-block communication). Coalesced row-major H sweep; per-edge LDS-atomic
// slot claim (row) + list append (column); coalesced dump to ws.
// Slot/list order scrambling is output-safe: row reductions are commutative,
// ab==m1 exclusion is order-free (R11), col-sum order shift = fp noise only.
__global__ __launch_bounds__(1024) void build_one(const float* __restrict__ H,
                                                  int* __restrict__ ws) {
    __shared__ int rcnt[CN];
    __shared__ int ccnt[VN];
    __shared__ int csc[CCAP * VN];
    const int t = threadIdx.x;

    for (int i = t; i < CN; i += 1024) rcnt[i] = 0;
    for (int i = t; i < VN; i += 1024) ccnt[i] = 0;
    for (int i = t; i < CCAP * VN; i += 1024) csc[i] = 0;   // safe default ids
    __syncthreads();

    for (int i = t; i < CN * VN; i += 1024) {               // coalesced H sweep
        if (H[i] > 0.5f) {
            const int c = i / VN, v = i - c * VN;
            const int l = atomicAdd(&rcnt[c], 1);
            if (l < RCAP) {
                const int pos = atomicAdd(&ccnt[v], 1);
                if (pos < CCAP) csc[pos * VN + v] = edge_id(l, c);
            }
        }
    }
    __syncthreads();

    for (int i = t; i < CN; i += 1024) ws[WS_RLEN + i] = rcnt[i];
    for (int i = t; i < VN; i += 1024) ws[WS_CCNT + i] = min(ccnt[i], CCAP);
    for (int i = t; i < CCAP * VN; i += 1024) ws[WS_CSC + i] = csc[i];
}

// ---- decode: byte-identical to R11 (proven best), ws offsets only ----
__global__ __launch_bounds__(TPB) void ldpc_decode(const float* __restrict__ r,
                                                   const float* __restrict__ alpha,
                                                   const int* __restrict__ ws,
                                                   float* __restrict__ out) {
    __shared__ float4 M4[NQ * CN];     // 18.4 KB
    float* const Mf = reinterpret_cast<float*>(M4);

    const int b = blockIdx.x;
    const int t = threadIdx.x;
    const float a_[NITER] = { alpha[0], alpha[1], alpha[2] };

    // per-thread columns v = t + q*TPB
    int ent4[3][4], entX[3][4];
    int cnt[3];
    float rv[3];
    #pragma unroll
    for (int q = 0; q < 3; ++q) {
        const int v = t + q * TPB;
        rv[q]  = r[b * VN + v];
        cnt[q] = ws[WS_CCNT + v];
        #pragma unroll
        for (int j = 0; j < 4; ++j) ent4[q][j] = ws[WS_CSC + j * VN + v];
    }
    const int rl = (t < CN) ? min(ws[WS_RLEN + t], RCAP) : 0;
    const int any_hi = __syncthreads_or((cnt[0] > 4) | (cnt[1] > 4) | (cnt[2] > 4));
    if (any_hi) {
        #pragma unroll
        for (int q = 0; q < 3; ++q)
            #pragma unroll
            for (int j = 0; j < 4; ++j) entX[q][j] = ws[WS_CSC + (4 + j) * VN + t + q * TPB];
    }

    // INF pads up to quad boundary (preserved across iterations)
    if (t < CN) {
        const int rpad = (rl + 3) & ~3;
        for (int k = rl; k < rpad; ++k) Mf[edge_id(k, t)] = INFINITY;
    }
    // M init = r on real edges (disjoint from pads)
    #pragma unroll
    for (int q = 0; q < 3; ++q) {
        #pragma unroll
        for (int j = 0; j < 4; ++j) if (j < cnt[q]) Mf[ent4[q][j]] = rv[q];
    }
    if (any_hi) {
        #pragma unroll
        for (int q = 0; q < 3; ++q) {
            #pragma unroll
            for (int j = 0; j < 4; ++j) if (4 + j < cnt[q]) Mf[entX[q][j]] = rv[q];
        }
    }
    __syncthreads();

    #pragma unroll
    for (int it = 0; it < NITER; ++it) {
        const float a = a_[it];

        // Pass A: 5-op two-smallest scan (no argmin), register-cached quads,
        // writeback E in place with equality-based exclusion (bit-exact).
        if (t < CN) {
            const int nq  = (rl + 3) >> 2;
            const int nqf = rl >> 2;
            float4 mq[NQ];                          // statically indexed (unrolled)
            uint32_t m1 = 0x7fffffffu, m2 = 0x7fffffffu, sg = 0u;
            #pragma unroll
            for (int q4 = 0; q4 < NQ; ++q4) {
                if (q4 < nq) {
                    mq[q4] = M4[q4 * CN + t];
                    const uint32_t* mu = reinterpret_cast<const uint32_t*>(&mq[q4]);
                    #pragma unroll
                    for (int j = 0; j < 4; ++j) {
                        const uint32_t mb = mu[j];
                        const uint32_t ab = mb & 0x7fffffffu;  // INF pads never win
                        sg ^= mb;
                        const uint32_t hi = (ab > m1) ? ab : m1;
                        m1 = (ab < m1) ? ab : m1;
                        m2 = (hi < m2) ? hi : m2;
                    }
                }
            }
            sg &= 0x80000000u;                              // pads are +INF: sign +1
            const uint32_t p1b = __float_as_uint(a * __uint_as_float(m1)) ^ sg;
            const uint32_t p2b = __float_as_uint(a * __uint_as_float(m2)) ^ sg;
            // exclusion by ab==m1: unique min -> exact argmin; ties -> p1b==p2b
            #pragma unroll
            for (int q4 = 0; q4 < NQ; ++q4) {
                if (q4 < nq) {
                    const uint32_t* mu = reinterpret_cast<const uint32_t*>(&mq[q4]);
                    float4 ev;
                    uint32_t* eu = reinterpret_cast<uint32_t*>(&ev);
                    if (q4 < nqf) {                         // full quad
                        #pragma unroll
                        for (int j = 0; j < 4; ++j) {
                            const uint32_t mb = mu[j];
                            const uint32_t ab = mb & 0x7fffffffu;
                            eu[j] = ((ab == m1) ? p2b : p1b) ^ (mb & 0x80000000u);
                        }
                    } else {                                // tail quad: keep INF pads
                        #pragma unroll
                        for (int j = 0; j < 4; ++j) {
                            const int k = q4 * 4 + j;
                            const uint32_t mb = mu[j];
                            const uint32_t ab = mb & 0x7fffffffu;
                            eu[j] = (k < rl)
                                  ? (((ab == m1) ? p2b : p1b) ^ (mb & 0x80000000u))
                                  : mb;
                        }
                    }
                    M4[q4 * CN + t] = ev;
                }
            }
        }
        __syncthreads();

        // Pass B: per-column gather of E, col-sum (CSC list order), fused M update
        #pragma unroll
        for (int q = 0; q < 3; ++q) {
            float E4[4], EX[4];
            float col = 0.0f;
            #pragma unroll
            for (int j = 0; j < 4; ++j) {
                E4[j] = (j < cnt[q]) ? Mf[ent4[q][j]] : 0.0f;
                col += E4[j];
            }
            if (any_hi) {
                #pragma unroll
                for (int j = 0; j < 4; ++j) {
                    EX[j] = (4 + j < cnt[q]) ? Mf[entX[q][j]] : 0.0f;
                    col += EX[j];
                }
            }
            if (it == NITER - 1) {
                out[b * VN + t + q * TPB] = rv[q] + col;
            } else {
                const float mb = col + rv[q];
                #pragma unroll
                for (int j = 0; j < 4; ++j) if (j < cnt[q]) Mf[ent4[q][j]] = mb - E4[j];
                if (any_hi) {
                    #pragma unroll
                    for (int j = 0; j < 4; ++j) if (4 + j < cnt[q]) Mf[entX[q][j]] = mb - EX[j];
                }
            }
        }
        if (it < NITER - 1) __syncthreads();
    }
}

extern "C" void kernel_launch(void* const* d_in, const int* in_sizes, int n_in,
                              void* d_out, int out_size, void* d_ws, size_t ws_size,
                              hipStream_t stream) {
    const float* r     = (const float*)d_in[0];
    const float* alpha = (const float*)d_in[1];
    const float* H     = (const float*)d_in[2];
    float* out = (float*)d_out;
    int* ws    = (int*)d_ws;

    build_one<<<1, 1024, 0, stream>>>(H, ws);
    ldpc_decode<<<BN, TPB, 0, stream>>>(r, alpha, ws, out);
}

// Round 14
// 35.917 us; speedup vs baseline: 1.0463x; 1.0463x over previous
//
#include <hip/hip_runtime.h>
#include <stdint.h>

#define CN 144
#define VN 576
#define BN 1024
#define NITER 3
#define RCAP 32      // row-weight capacity, multiple of 4 (actual max ~28; R9-R13-proven)
#define NQ   (RCAP/4)
#define CCAP 8       // column-weight capacity (actual 4, rare 5)
#define TPB 64       // ONE wave per block: barriers are free, no inter-wave convoy
#define CPT 9        // columns per thread: 576/64

// ws layout (ints):
#define WS_RLEN 0                    // [0,144)  row lengths
#define WS_LOC  192                  // [+CN*VN)  loc[v*CN+c] = slot in row, -1 if none
#define WS_CSC  (192 + CN*VN)        // [+CCAP*VN) slot-major [j][v] = edge id
#define WS_CCNT (WS_CSC + CCAP*VN)   // [+VN)

// edge id for (row-slot l, check c), quad layout: float index
// ((l>>2)*CN + c)*4 + (l&3) -> lane-consecutive float4 per (l>>2, c)
__device__ __forceinline__ int edge_id(int l, int c) {
    return (((l >> 2) * CN + c) << 2) | (l & 3);
}

// ---- build 1 (R5/R11-proven): per-row ballot compaction -> loc + row lengths ----
__global__ __launch_bounds__(64) void build_stage(const float* __restrict__ H,
                                                  int* __restrict__ ws) {
    const int c = blockIdx.x;          // 144 blocks
    const int lane = threadIdx.x;      // 64
    int base = 0;
    const float* row = H + c * VN;
    for (int ch = 0; ch < VN / 64; ++ch) {
        const int v = ch * 64 + lane;
        const bool set = row[v] > 0.5f;
        const unsigned long long mask = __ballot(set);
        const int off = base + (int)__popcll(mask & ((1ULL << lane) - 1ULL));
        ws[WS_LOC + v * CN + c] = set ? off : -1;   // ascending-v slot order
        base += (int)__popcll(mask);
    }
    if (lane == 0) ws[WS_RLEN + c] = base;
}

// ---- build 2 (R5/R11-proven): one wave per column -> slot-major CSC ----
__global__ __launch_bounds__(64) void build_csc(int* __restrict__ ws) {
    const int v = blockIdx.x;          // 576 blocks
    const int lane = threadIdx.x;      // 64
    int cnt = 0;
    for (int ch = 0; ch < 3; ++ch) {
        const int c = ch * 64 + lane;
        const int l = (c < CN) ? ws[WS_LOC + v * CN + c] : -1;   // coalesced
        const bool set = (l >= 0) && (l < RCAP);
        const unsigned long long mask = __ballot(set);
        const int off = cnt + (int)__popcll(mask & ((1ULL << lane) - 1ULL));
        if (set && off < CCAP) ws[WS_CSC + off * VN + v] = edge_id(l, c);
        cnt += (int)__popcll(mask);
    }
    if (cnt > CCAP) cnt = CCAP;
    if (lane == 0) ws[WS_CCNT + v] = cnt;
    if (lane >= cnt && lane < CCAP) ws[WS_CSC + lane * VN + v] = 0;  // defined, unused
}

// ---- decode: one block = ONE WAVE per batch item; 9 cols + 2-3 checks per thread.
// Pass A body is R11's proven 5-op scan + reg-quad cache; barriers cost ~nothing
// at 1 wave/block, and 4 independent blocks/CU hide each other's LDS latency.
__global__ __launch_bounds__(TPB) void ldpc_decode(const float* __restrict__ r,
                                                   const float* __restrict__ alpha,
                                                   const int* __restrict__ ws,
                                                   float* __restrict__ out) {
    __shared__ float4 M4[NQ * CN];     // 18.4 KB
    float* const Mf = reinterpret_cast<float*>(M4);

    const int b = blockIdx.x;
    const int t = threadIdx.x;
    const float a_[NITER] = { alpha[0], alpha[1], alpha[2] };

    // per-thread columns v = t + k*64 (coalesced)
    int   ent4[CPT][4], entX[CPT][4];
    int   cnt[CPT];
    float rv[CPT];
    #pragma unroll
    for (int k = 0; k < CPT; ++k) {
        const int v = t + k * 64;
        rv[k]  = r[b * VN + v];
        cnt[k] = ws[WS_CCNT + v];
        #pragma unroll
        for (int j = 0; j < 4; ++j) ent4[k][j] = ws[WS_CSC + j * VN + v];
    }
    bool hi = false;
    #pragma unroll
    for (int k = 0; k < CPT; ++k) hi |= (cnt[k] > 4);
    const bool any_hi = __any(hi);      // wave covers all 576 cols -> block-uniform
    if (any_hi) {
        #pragma unroll
        for (int k = 0; k < CPT; ++k)
            #pragma unroll
            for (int j = 0; j < 4; ++j) entX[k][j] = ws[WS_CSC + (4 + j) * VN + t + k * 64];
    }

    // per-thread checks c = t + cr*64 (cr=0,1 always; cr=2 only t<16)
    int rl[3];
    #pragma unroll
    for (int cr = 0; cr < 3; ++cr) {
        const int c = t + cr * 64;
        rl[cr] = (c < CN) ? min(ws[WS_RLEN + c], RCAP) : 0;
    }

    // INF pads up to quad boundary (preserved across iterations)
    #pragma unroll
    for (int cr = 0; cr < 3; ++cr) {
        const int c = t + cr * 64;
        if (c < CN) {
            const int rpad = (rl[cr] + 3) & ~3;
            for (int k = rl[cr]; k < rpad; ++k) Mf[edge_id(k, c)] = INFINITY;
        }
    }
    // M init = r on real edges (disjoint from pads)
    #pragma unroll
    for (int k = 0; k < CPT; ++k) {
        #pragma unroll
        for (int j = 0; j < 4; ++j) if (j < cnt[k]) Mf[ent4[k][j]] = rv[k];
    }
    if (any_hi) {
        #pragma unroll
        for (int k = 0; k < CPT; ++k) {
            #pragma unroll
            for (int j = 0; j < 4; ++j) if (4 + j < cnt[k]) Mf[entX[k][j]] = rv[k];
        }
    }
    __syncthreads();

    #pragma unroll
    for (int it = 0; it < NITER; ++it) {
        const float a = a_[it];

        // Pass A: per-check rounds; R11's 5-op scan + reg-quad cache + in-place E.
        #pragma unroll
        for (int cr = 0; cr < 3; ++cr) {
            const int c = t + cr * 64;
            if (c < CN) {
                const int rlc = rl[cr];
                const int nq  = (rlc + 3) >> 2;
                const int nqf = rlc >> 2;
                float4 mq[NQ];                      // statically indexed (unrolled)
                uint32_t m1 = 0x7fffffffu, m2 = 0x7fffffffu, sg = 0u;
                #pragma unroll
                for (int q4 = 0; q4 < NQ; ++q4) {
                    if (q4 < nq) {
                        mq[q4] = M4[q4 * CN + c];
                        const uint32_t* mu = reinterpret_cast<const uint32_t*>(&mq[q4]);
                        #pragma unroll
                        for (int j = 0; j < 4; ++j) {
                            const uint32_t mb = mu[j];
                            const uint32_t ab = mb & 0x7fffffffu;  // INF pads never win
                            sg ^= mb;
                            const uint32_t hi2 = (ab > m1) ? ab : m1;
                            m1 = (ab < m1) ? ab : m1;
                            m2 = (hi2 < m2) ? hi2 : m2;
                        }
                    }
                }
                sg &= 0x80000000u;                          // pads are +INF: sign +1
                const uint32_t p1b = __float_as_uint(a * __uint_as_float(m1)) ^ sg;
                const uint32_t p2b = __float_as_uint(a * __uint_as_float(m2)) ^ sg;
                // exclusion by ab==m1: unique min -> exact argmin; ties -> p1b==p2b
                #pragma unroll
                for (int q4 = 0; q4 < NQ; ++q4) {
                    if (q4 < nq) {
                        const uint32_t* mu = reinterpret_cast<const uint32_t*>(&mq[q4]);
                        float4 ev;
                        uint32_t* eu = reinterpret_cast<uint32_t*>(&ev);
                        if (q4 < nqf) {                     // full quad
                            #pragma unroll
                            for (int j = 0; j < 4; ++j) {
                                const uint32_t mb = mu[j];
                                const uint32_t ab = mb & 0x7fffffffu;
                                eu[j] = ((ab == m1) ? p2b : p1b) ^ (mb & 0x80000000u);
                            }
                        } else {                            // tail quad: keep INF pads
                            #pragma unroll
                            for (int j = 0; j < 4; ++j) {
                                const int k = q4 * 4 + j;
                                const uint32_t mb = mu[j];
                                const uint32_t ab = mb & 0x7fffffffu;
                                eu[j] = (k < rlc)
                                      ? (((ab == m1) ? p2b : p1b) ^ (mb & 0x80000000u))
                                      : mb;
                            }
                        }
                        M4[q4 * CN + c] = ev;
                    }
                }
            }
        }
        __syncthreads();   // 1-wave block: s_barrier is immediate, just orders LDS

        // Pass B: per-column gather of E (ascending c), col-sum, fused M update
        #pragma unroll
        for (int k = 0; k < CPT; ++k) {
            float E4[4], EX[4];
            float col = 0.0f;
            #pragma unroll
            for (int j = 0; j < 4; ++j) {
                E4[j] = (j < cnt[k]) ? Mf[ent4[k][j]] : 0.0f;
                col += E4[j];
            }
            if (any_hi) {
                #pragma unroll
                for (int j = 0; j < 4; ++j) {
                    EX[j] = (4 + j < cnt[k]) ? Mf[entX[k][j]] : 0.0f;
                    col += EX[j];
                }
            }
            if (it == NITER - 1) {
                out[b * VN + t + k * 64] = rv[k] + col;
            } else {
                const float mb = col + rv[k];
                #pragma unroll
                for (int j = 0; j < 4; ++j) if (j < cnt[k]) Mf[ent4[k][j]] = mb - E4[j];
                if (any_hi) {
                    #pragma unroll
                    for (int j = 0; j < 4; ++j) if (4 + j < cnt[k]) Mf[entX[k][j]] = mb - EX[j];
                }
            }
        }
        if (it < NITER - 1) __syncthreads();
    }
}

extern "C" void kernel_launch(void* const* d_in, const int* in_sizes, int n_in,
                              void* d_out, int out_size, void* d_ws, size_t ws_size,
                              hipStream_t stream) {
    const float* r     = (const float*)d_in[0];
    const float* alpha = (const float*)d_in[1];
    const float* H     = (const float*)d_in[2];
    float* out = (float*)d_out;
    int* ws    = (int*)d_ws;

    build_stage<<<CN, 64, 0, stream>>>(H, ws);
    build_csc<<<VN, 64, 0, stream>>>(ws);
    ldpc_decode<<<BN, TPB, 0, stream>>>(r, alpha, ws, out);
}

// Round 15
// 20.621 us; speedup vs baseline: 1.8224x; 1.7418x over previous
//
#include <hip/hip_runtime.h>
#include <stdint.h>

#define CN 144
#define VN 576
#define BN 1024
#define NITER 3
#define RCAP 32      // row-weight capacity, multiple of 4 (actual max ~28; R9-R14-proven)
#define NQ   (RCAP/4)
#define CCAP 8       // column-weight capacity (actual 4, rare 5)
#define TPB 192      // 3 waves; 576/192 = exactly 3 columns per thread (R11-proven)

// ws layout (ints):
#define WS_RLEN 0                 // [0,144)   raw row lengths (redundant same-value writes)
#define WS_CCNT 144               // [144,720) per-column edge count (clamped to CCAP)
#define WS_CSC  720               // [720, 720+CCAP*VN) slot-major [j][v] = edge id

// edge id for (row-slot l, check c), quad layout: float index
// ((l>>2)*CN + c)*4 + (l&3) -> lane-consecutive float4 per (l>>2, c)
__device__ __forceinline__ int edge_id(int l, int c) {
    return (((l >> 2) * CN + c) << 2) | (l & 3);
}

// ---- single build kernel: one wave per column. Finds member checks via
// chunked column ballot (ascending c), then per member row computes the
// ascending-v slot (prefix popcount before v) AND raw row length via 9
// coalesced chunk-ballots. No atomics, no cross-block intermediates; the only
// shared writes (WS_RLEN[c]) carry identical values from every writer ->
// benign and order-independent. Bit-identical CSC/slots to the R11 build.
__global__ __launch_bounds__(64) void build_combined(const float* __restrict__ H,
                                                     int* __restrict__ ws) {
    const int v = blockIdx.x;          // 576 blocks
    const int lane = threadIdx.x;      // 64
    __shared__ int rows[CCAP];         // member check ids, ascending c

    int cn = 0;                        // wave-uniform running count
    for (int ch = 0; ch < 3; ++ch) {
        const int c = ch * 64 + lane;
        const bool set = (c < CN) && (H[c * VN + v] > 0.5f);
        const unsigned long long mask = __ballot(set);
        const int off = cn + (int)__popcll(mask & ((1ULL << lane) - 1ULL));
        if (set && off < CCAP) rows[off] = c;
        cn += (int)__popcll(mask);
    }
    const int nr = min(cn, CCAP);
    __syncthreads();                   // publish rows[] (1 wave: cheap)

    const int vch = v >> 6, vbit = v & 63;
    for (int j = 0; j < nr; ++j) {
        const int c = rows[j];         // wave-uniform
        int pre = 0, tot = 0;
        for (int ch = 0; ch < 9; ++ch) {               // coalesced row sweep
            const bool s = H[c * VN + ch * 64 + lane] > 0.5f;
            const unsigned long long m = __ballot(s);
            tot += (int)__popcll(m);
            if (ch < vch)       pre += (int)__popcll(m);
            else if (ch == vch) pre += (int)__popcll(m & ((1ULL << vbit) - 1ULL));
        }
        if (lane == 0) {
            ws[WS_CSC + j * VN + v] = (pre < RCAP) ? edge_id(pre, c) : 0;
            ws[WS_RLEN + c] = tot;     // identical value from every column of c
        }
    }
    if (lane == 0) ws[WS_CCNT + v] = nr;
    if (lane >= nr && lane < CCAP) ws[WS_CSC + lane * VN + v] = 0;  // defined, unused
}

// ---- decode: byte-identical to R11 (proven best, 23.7 us), ws offsets only ----
__global__ __launch_bounds__(TPB) void ldpc_decode(const float* __restrict__ r,
                                                   const float* __restrict__ alpha,
                                                   const int* __restrict__ ws,
                                                   float* __restrict__ out) {
    __shared__ float4 M4[NQ * CN];     // 18.4 KB
    float* const Mf = reinterpret_cast<float*>(M4);

    const int b = blockIdx.x;
    const int t = threadIdx.x;
    const float a_[NITER] = { alpha[0], alpha[1], alpha[2] };

    // per-thread columns v = t + q*TPB
    int ent4[3][4], entX[3][4];
    int cnt[3];
    float rv[3];
    #pragma unroll
    for (int q = 0; q < 3; ++q) {
        const int v = t + q * TPB;
        rv[q]  = r[b * VN + v];
        cnt[q] = ws[WS_CCNT + v];
        #pragma unroll
        for (int j = 0; j < 4; ++j) ent4[q][j] = ws[WS_CSC + j * VN + v];
    }
    const int rl = (t < CN) ? min(ws[WS_RLEN + t], RCAP) : 0;
    const int any_hi = __syncthreads_or((cnt[0] > 4) | (cnt[1] > 4) | (cnt[2] > 4));
    if (any_hi) {
        #pragma unroll
        for (int q = 0; q < 3; ++q)
            #pragma unroll
            for (int j = 0; j < 4; ++j) entX[q][j] = ws[WS_CSC + (4 + j) * VN + t + q * TPB];
    }

    // INF pads up to quad boundary (preserved across iterations)
    if (t < CN) {
        const int rpad = (rl + 3) & ~3;
        for (int k = rl; k < rpad; ++k) Mf[edge_id(k, t)] = INFINITY;
    }
    // M init = r on real edges (disjoint from pads)
    #pragma unroll
    for (int q = 0; q < 3; ++q) {
        #pragma unroll
        for (int j = 0; j < 4; ++j) if (j < cnt[q]) Mf[ent4[q][j]] = rv[q];
    }
    if (any_hi) {
        #pragma unroll
        for (int q = 0; q < 3; ++q) {
            #pragma unroll
            for (int j = 0; j < 4; ++j) if (4 + j < cnt[q]) Mf[entX[q][j]] = rv[q];
        }
    }
    __syncthreads();

    #pragma unroll
    for (int it = 0; it < NITER; ++it) {
        const float a = a_[it];

        // Pass A: 5-op two-smallest scan (no argmin), register-cached quads,
        // writeback E in place with equality-based exclusion (bit-exact).
        if (t < CN) {
            const int nq  = (rl + 3) >> 2;
            const int nqf = rl >> 2;
            float4 mq[NQ];                          // statically indexed (unrolled)
            uint32_t m1 = 0x7fffffffu, m2 = 0x7fffffffu, sg = 0u;
            #pragma unroll
            for (int q4 = 0; q4 < NQ; ++q4) {
                if (q4 < nq) {
                    mq[q4] = M4[q4 * CN + t];
                    const uint32_t* mu = reinterpret_cast<const uint32_t*>(&mq[q4]);
                    #pragma unroll
                    for (int j = 0; j < 4; ++j) {
                        const uint32_t mb = mu[j];
                        const uint32_t ab = mb & 0x7fffffffu;  // INF pads never win
                        sg ^= mb;
                        const uint32_t hi = (ab > m1) ? ab : m1;
                        m1 = (ab < m1) ? ab : m1;
                        m2 = (hi < m2) ? hi : m2;
                    }
                }
            }
            sg &= 0x80000000u;                              // pads are +INF: sign +1
            const uint32_t p1b = __float_as_uint(a * __uint_as_float(m1)) ^ sg;
            const uint32_t p2b = __float_as_uint(a * __uint_as_float(m2)) ^ sg;
            // exclusion by ab==m1: unique min -> exact argmin; ties -> p1b==p2b
            #pragma unroll
            for (int q4 = 0; q4 < NQ; ++q4) {
                if (q4 < nq) {
                    const uint32_t* mu = reinterpret_cast<const uint32_t*>(&mq[q4]);
                    float4 ev;
                    uint32_t* eu = reinterpret_cast<uint32_t*>(&ev);
                    if (q4 < nqf) {                         // full quad
                        #pragma unroll
                        for (int j = 0; j < 4; ++j) {
                            const uint32_t mb = mu[j];
                            const uint32_t ab = mb & 0x7fffffffu;
                            eu[j] = ((ab == m1) ? p2b : p1b) ^ (mb & 0x80000000u);
                        }
                    } else {                                // tail quad: keep INF pads
                        #pragma unroll
                        for (int j = 0; j < 4; ++j) {
                            const int k = q4 * 4 + j;
                            const uint32_t mb = mu[j];
                            const uint32_t ab = mb & 0x7fffffffu;
                            eu[j] = (k < rl)
                                  ? (((ab == m1) ? p2b : p1b) ^ (mb & 0x80000000u))
                                  : mb;
                        }
                    }
                    M4[q4 * CN + t] = ev;
                }
            }
        }
        __syncthreads();

        // Pass B: per-column gather of E (ascending c), col-sum, fused M update
        #pragma unroll
        for (int q = 0; q < 3; ++q) {
            float E4[4], EX[4];
            float col = 0.0f;
            #pragma unroll
            for (int j = 0; j < 4; ++j) {
                E4[j] = (j < cnt[q]) ? Mf[ent4[q][j]] : 0.0f;
                col += E4[j];
            }
            if (any_hi) {
                #pragma unroll
                for (int j = 0; j < 4; ++j) {
                    EX[j] = (4 + j < cnt[q]) ? Mf[entX[q][j]] : 0.0f;
                    col += EX[j];
                }
            }
            if (it == NITER - 1) {
                out[b * VN + t + q * TPB] = rv[q] + col;
            } else {
                const float mb = col + rv[q];
                #pragma unroll
                for (int j = 0; j < 4; ++j) if (j < cnt[q]) Mf[ent4[q][j]] = mb - E4[j];
                if (any_hi) {
                    #pragma unroll
                    for (int j = 0; j < 4; ++j) if (4 + j < cnt[q]) Mf[entX[q][j]] = mb - EX[j];
                }
            }
        }
        if (it < NITER - 1) __syncthreads();
    }
}

extern "C" void kernel_launch(void* const* d_in, const int* in_sizes, int n_in,
                              void* d_out, int out_size, void* d_ws, size_t ws_size,
                              hipStream_t stream) {
    const float* r     = (const float*)d_in[0];
    const float* alpha = (const float*)d_in[1];
    const float* H     = (const float*)d_in[2];
    float* out = (float*)d_out;
    int* ws    = (int*)d_ws;

    build_combined<<<VN, 64, 0, stream>>>(H, ws);
    ldpc_decode<<<BN, TPB, 0, stream>>>(r, alpha, ws, out);
}